// Round 22
// baseline (71.275 us; speedup 1.0000x reference)
//
#include <hip/hip_runtime.h>
#include <hip/hip_bf16.h>
#include <stdint.h>

#define NROWS 8192
#define DIM 512

typedef short bf16x8 __attribute__((ext_vector_type(8)));
typedef float f32x4 __attribute__((ext_vector_type(4)));

__device__ __forceinline__ unsigned short f2bf(float f) {
    union { float f; uint32_t u; } c; c.f = f;
    uint32_t u = c.u;
    return (unsigned short)((u + 0x7FFFu + ((u >> 16) & 1u)) >> 16);
}

__device__ __forceinline__ void gload16(const unsigned short* g, unsigned short* l) {
    __builtin_amdgcn_global_load_lds((const __attribute__((address_space(1))) void*)g,
                                     (__attribute__((address_space(3))) void*)l,
                                     16, 0, 0);
}

// ---------------- Kernel 1: L2-normalize rows -> bf16; zero out[0] + split-lin slots --
__global__ __launch_bounds__(256) void knorm(const float* __restrict__ in,
                                             unsigned short* __restrict__ out,
                                             float* __restrict__ part,
                                             float* __restrict__ loss_out) {
    if (blockIdx.x == 0 && threadIdx.x == 0) loss_out[0] = 0.0f;
    if (blockIdx.x < 16) {   // zero the 16 split-tile partial slots (sixteenths atomicAdd)
        part[((164 + blockIdx.x) << 9) + threadIdx.x] = 0.0f;
        part[((164 + blockIdx.x) << 9) + 256 + threadIdx.x] = 0.0f;
    }
    const int row  = (blockIdx.x << 2) + (threadIdx.x >> 6);
    const int lane = threadIdx.x & 63;
    const float4* src = (const float4*)(in + (size_t)row * DIM);
    float4 a = src[lane];
    float4 b = src[lane + 64];
    float ss = a.x*a.x + a.y*a.y + a.z*a.z + a.w*a.w
             + b.x*b.x + b.y*b.y + b.z*b.z + b.w*b.w;
    #pragma unroll
    for (int m = 1; m < 64; m <<= 1) ss += __shfl_xor(ss, m);
    const float inv = 1.0f / sqrtf(ss);
    ushort4* dst = (ushort4*)(out + (size_t)row * DIM);
    ushort4 o;
    o.x = f2bf(a.x*inv); o.y = f2bf(a.y*inv); o.z = f2bf(a.z*inv); o.w = f2bf(a.w*inv);
    dst[lane] = o;
    o.x = f2bf(b.x*inv); o.y = f2bf(b.y*inv); o.z = f2bf(b.z*inv); o.w = f2bf(b.w*inv);
    dst[lane + 64] = o;
}

// ---------------- Kernel 2: 512 full 256^2 tiles; blocks f<256 ALSO run one inline
// sixteenth (64^2) tile after their full tile.
// R20 lesson: tail-block time (~9us) is work-INVARIANT even at 1 convoy -> the
// third scheduling wave itself (round-2 jitter + block restart) is the cost,
// not block internals. Fix: NO third wave. 512 blocks = exactly 2 rounds;
// the 16 split tiles (lins 164..179) are covered by 256 inline sixteenths
// (q = f) appended to the round-1 blocks (f<256, launched first): stage
// 64rows x 1KB x 2 ops = 128 KB in ONE shot (8 gload16/thread, wave stages
// whole rows, stored group l = data group l^(r&7), r&7==w&7), vmcnt(0) +
// one barrier, 16 unbarriered LDS->MFMA K-steps, ~128 atomicAdds into the
// pre-zeroed split slots. Worst-case downside ~0: even if a CU gets two
// extended blocks, 2 x ~23us matches the current 47.6us kgemm.
__global__ __launch_bounds__(1024, 1) void kgemm(const unsigned short* __restrict__ E,
                                                 float* __restrict__ part,
                                                 float* __restrict__ pospart) {
    __shared__ unsigned short lds[2][2][256 * 64];   // 128 KB

    const int tid = threadIdx.x;
    const int w = tid >> 6;          // 0..15
    const int l = tid & 63;
    const int xcd  = blockIdx.x & 7;
    const int slot = blockIdx.x >> 3;                // 0..63
    const int g_src = (l & 7) ^ (l >> 3);   // inverse-swizzled source 16B-group

    // ================= FULL: 256x256 tile (R18 verbatim) =============================
    const int f   = (xcd << 6) + slot;               // 0..511
    const int lin = f + (f >= 164 ? 16 : 0);         // skip split set 164..179
    int rem = lin;
    int SI = -1, SJ = -1;
    #pragma unroll
    for (int s = 0; s < 10; s++) {
        constexpr int si_t[10] = {0,0,0,0,1,1,1,2,2,3};
        constexpr int sj_t[10] = {0,1,2,3,1,2,3,2,3,3};
        const int sz = (si_t[s] == sj_t[s]) ? 36 : 64;
        if (SI < 0) {
            if (rem < sz) { SI = si_t[s]; SJ = sj_t[s]; }
            else rem -= sz;
        }
    }
    int bi, bj;
    if (SI == SJ) {
        int x = 0;
        while (rem >= 8 - x) { rem -= 8 - x; x++; }
        bi = (SI << 3) + x; bj = (SI << 3) + x + rem;
    } else {
        bi = (SI << 3) + (rem >> 3);
        bj = (SJ << 3) + (rem & 7);
    }

    const int brow = bi << 8;
    const int bcol = bj << 8;
    const int wr = (w >> 2) << 6;
    const int wc = (w & 3) << 6;

    f32x4 acc[4][4];
    #pragma unroll
    for (int i = 0; i < 4; i++)
        #pragma unroll
        for (int j = 0; j < 4; j++) acc[i][j] = (f32x4)0.0f;

    auto STAGE = [&](int buf, int kt) {
        const size_t colb = (size_t)((kt << 6) + (g_src << 3));
        #pragma unroll
        for (int s = 0; s < 2; s++) {
            const int rb = (w << 4) + (s << 3);
            const int r  = rb + (l >> 3);
            gload16(E + (size_t)(brow + r) * DIM + colb, &lds[buf][0][rb << 6]);
            gload16(E + (size_t)(bcol + r) * DIM + colb, &lds[buf][1][rb << 6]);
        }
    };

    auto COMPUTE = [&](int buf) {
        const unsigned short* sA = lds[buf][0];
        const unsigned short* sB = lds[buf][1];
        #pragma unroll
        for (int kk = 0; kk < 2; kk++) {
            bf16x8 aF[4], bF[4];
            const int gk  = (kk << 2) + (l >> 4);
            const int gsw = (gk ^ (l & 7)) << 3;
            #pragma unroll
            for (int mi = 0; mi < 4; mi++) {
                const int rr = wr + (mi << 4) + (l & 15);
                aF[mi] = *(const bf16x8*)&sA[(rr << 6) + gsw];
            }
            #pragma unroll
            for (int ni = 0; ni < 4; ni++) {
                const int rr = wc + (ni << 4) + (l & 15);
                bF[ni] = *(const bf16x8*)&sB[(rr << 6) + gsw];
            }
            #pragma unroll
            for (int mi = 0; mi < 4; mi++)
                #pragma unroll
                for (int ni = 0; ni < 4; ni++)
                    acc[mi][ni] = __builtin_amdgcn_mfma_f32_16x16x32_bf16(
                        aF[mi], bF[ni], acc[mi][ni], 0, 0, 0);
        }
    };

    STAGE(0, 0);
    #pragma unroll
    for (int kt = 0; kt < 8; kt++) {
        if (kt > 0) __builtin_amdgcn_s_barrier();
        if (kt < 7) {
            STAGE((kt + 1) & 1, kt + 1);
            asm volatile("s_waitcnt vmcnt(4)" ::: "memory");
        } else {
            asm volatile("s_waitcnt vmcnt(0)" ::: "memory");
        }
        __builtin_amdgcn_sched_barrier(0);
        __builtin_amdgcn_s_barrier();
        COMPUTE(kt & 1);
    }

    float* lds_row = (float*)&lds[0][0][0];       // [4][256]
    float* lds_col = lds_row + 1024;              // [4][256]
    float* lds_pos = lds_row + 2048;              // [4][256]

    __syncthreads();

    if (bi == bj) {
        #pragma unroll
        for (int mi = 0; mi < 4; mi++) {
            #pragma unroll
            for (int r = 0; r < 4; r++) {
                const int lrow = wr + (mi << 4) + ((l >> 4) << 2) + r;
                const int gi = brow + lrow;
                float p = 0.0f, n = 0.0f;
                #pragma unroll
                for (int ni = 0; ni < 4; ni++) {
                    const int gj = bcol + wc + (ni << 4) + (l & 15);
                    const float e = __expf(fmaf(acc[mi][ni][r], 10.0f, -10.0f));
                    if (gi == gj) {
                    } else if ((gi >> 2) == (gj >> 2)) {
                        p += e;
                    } else {
                        n += e;
                    }
                }
                #pragma unroll
                for (int m = 1; m < 16; m <<= 1) {
                    n += __shfl_xor(n, m);
                    p += __shfl_xor(p, m);
                }
                if ((l & 15) == 0) {
                    lds_row[((w & 3) << 8) + lrow] = n;
                    lds_pos[((w & 3) << 8) + lrow] = p;
                }
            }
        }
    } else {
        float c[4] = {0.0f, 0.0f, 0.0f, 0.0f};
        #pragma unroll
        for (int mi = 0; mi < 4; mi++) {
            #pragma unroll
            for (int r = 0; r < 4; r++) {
                const int lrow = wr + (mi << 4) + ((l >> 4) << 2) + r;
                float n = 0.0f;
                #pragma unroll
                for (int ni = 0; ni < 4; ni++) {
                    const float e = __expf(fmaf(acc[mi][ni][r], 10.0f, -10.0f));
                    n += e;
                    c[ni] += e;
                }
                #pragma unroll
                for (int m = 1; m < 16; m <<= 1) n += __shfl_xor(n, m);
                if ((l & 15) == 0) lds_row[((w & 3) << 8) + lrow] = n;
            }
        }
        #pragma unroll
        for (int ni = 0; ni < 4; ni++) {
            c[ni] += __shfl_xor(c[ni], 16);
            c[ni] += __shfl_xor(c[ni], 32);
            if ((l >> 4) == 0)
                lds_col[((w >> 2) << 8) + wc + (ni << 4) + l] = c[ni];
        }
    }
    __syncthreads();

    if (tid < 256) {
        const float s = lds_row[tid] + lds_row[256 + tid]
                      + lds_row[512 + tid] + lds_row[768 + tid];
        part[((size_t)lin << 9) + tid] = s;
    } else if (tid < 512) {
        if (bi != bj) {
            const int cc = tid - 256;
            const float s = lds_col[cc] + lds_col[256 + cc]
                          + lds_col[512 + cc] + lds_col[768 + cc];
            part[((size_t)lin << 9) + 256 + cc] = s;
        }
    } else if (tid < 768) {
        if (bi == bj) {
            const int rr = tid - 512;
            const float s = lds_pos[rr] + lds_pos[256 + rr]
                          + lds_pos[512 + rr] + lds_pos[768 + rr];
            pospart[(bi << 8) + rr] = s;
        }
    }

    // ============ INLINE SIXTEENTH (blocks f<256 only; q = f) ============
    if (f >= 256) return;
    __syncthreads();                                 // partial-store LDS reads done

    const int q     = f;
    const int p     = q >> 4;                        // parent 0..15
    const int lin2  = 164 + p;
    const int sbi   = p >> 3, sbj = 24 + (p & 7);
    const int qroff = ((q >> 2) & 3) << 6;
    const int qcoff = (q & 3) << 6;
    const int srow  = (sbi << 8) + qroff;
    const int scol  = (sbj << 8) + qcoff;
    const int swr   = (w >> 2) << 4;                 // 0,16,32,48
    const int swc   = (w & 3) << 4;                  // 0,16,32,48

    unsigned short* pA = &lds[0][0][0];              // 64 rows x 512 (64 KB)
    unsigned short* pB = pA + 64 * 512;              // 64 KB

    // one-shot staging: wave w stages rows s*16+w of A and B (whole 1KB rows);
    // lane l fills dest group l; source group = l ^ (w&7)  [r&7 == w&7].
    const int sg = (l ^ (w & 7)) << 3;
    #pragma unroll
    for (int s = 0; s < 4; s++) {
        const int r = (s << 4) + w;
        gload16(E + (size_t)(srow + r) * DIM + sg, &pA[(size_t)r * DIM]);
    }
    #pragma unroll
    for (int s = 0; s < 4; s++) {
        const int r = (s << 4) + w;
        gload16(E + (size_t)(scol + r) * DIM + sg, &pB[(size_t)r * DIM]);
    }
    asm volatile("s_waitcnt vmcnt(0)" ::: "memory");
    __builtin_amdgcn_sched_barrier(0);
    __builtin_amdgcn_s_barrier();                    // the only extra barrier

    f32x4 acc2 = (f32x4)0.0f;
    #pragma unroll
    for (int ks = 0; ks < 16; ks++) {
        const int gk  = (ks << 2) + (l >> 4);        // data 16B-group 0..63
        const int gsw = (gk ^ (l & 7)) << 3;         // stored (swizzled) offset
        bf16x8 aF = *(const bf16x8*)&pA[(size_t)(swr + (l & 15)) * DIM + gsw];
        bf16x8 bF = *(const bf16x8*)&pB[(size_t)(swc + (l & 15)) * DIM + gsw];
        acc2 = __builtin_amdgcn_mfma_f32_16x16x32_bf16(aF, bF, acc2, 0, 0, 0);
    }

    float c2 = 0.0f;
    #pragma unroll
    for (int r = 0; r < 4; r++) {
        const int lrow = swr + ((l >> 4) << 2) + r;  // 0..63
        const float e = __expf(fmaf(acc2[r], 10.0f, -10.0f));
        c2 += e;
        float n = e;
        #pragma unroll
        for (int m = 1; m < 16; m <<= 1) n += __shfl_xor(n, m);
        if ((l & 15) == 0)
            atomicAdd(&part[((size_t)lin2 << 9) + qroff + lrow], n);
    }
    c2 += __shfl_xor(c2, 16);
    c2 += __shfl_xor(c2, 32);
    if ((l >> 4) == 0)                               // l = 0..15 -> col swc+l
        atomicAdd(&part[((size_t)lin2 << 9) + 256 + qcoff + swc + l], c2);
}

// ---------------- Kernel 3: gather partials, compute loss, reduce ----------------
__global__ __launch_bounds__(128) void kred(const float* __restrict__ part,
                                            const float* __restrict__ pospart,
                                            float* __restrict__ out) {
    const int T = blockIdx.x >> 1;
    const int r = ((blockIdx.x & 1) << 7) + threadIdx.x;   // 0..255 within T's group

    auto linof = [](int a, int b) {   // a <= b, 0..31
        constexpr int base[4][4] = {{0, 36, 100, 164},
                                    {0, 228, 264, 328},
                                    {0, 0, 392, 428},
                                    {0, 0, 0, 492}};
        const int SI = a >> 3, SJ = b >> 3, x = a & 7, y = b & 7;
        int inner;
        if (SI == SJ) inner = (x << 3) - ((x * (x - 1)) >> 1) + (y - x);
        else          inner = (x << 3) + y;
        return base[SI][SJ] + inner;
    };

    float n = 0.0f;
    for (int bj = T; bj < 32; bj++)
        n += part[((size_t)linof(T, bj) << 9) + r];
    for (int bi = 0; bi < T; bi++)
        n += part[((size_t)linof(bi, T) << 9) + 256 + r];
    const float p = pospart[(T << 8) + r];

    float s = __logf(p + n + 1e-8f) - __logf(p);
    #pragma unroll
    for (int m = 1; m < 64; m <<= 1) s += __shfl_xor(s, m);
    __shared__ float red[2];
    if ((threadIdx.x & 63) == 0) red[threadIdx.x >> 6] = s;
    __syncthreads();
    if (threadIdx.x == 0)
        atomicAdd(out, (red[0] + red[1]) * (1.0f / (float)NROWS));
}

extern "C" void kernel_launch(void* const* d_in, const int* in_sizes, int n_in,
                              void* d_out, int out_size, void* d_ws, size_t ws_size,
                              hipStream_t stream) {
    (void)in_sizes; (void)n_in; (void)out_size; (void)ws_size;
    const float* emb = (const float*)d_in[0];
    unsigned short* En = (unsigned short*)d_ws;                          // 8 MB bf16
    float* pospart = (float*)((char*)d_ws + (size_t)NROWS * DIM * 2);    // 32 KB
    float* part    = pospart + 32 * 256;                                 // 1.05 MB

    knorm<<<NROWS / 4, 256, 0, stream>>>(emb, En, part, (float*)d_out);
    kgemm<<<512, 1024, 0, stream>>>(En, part, pospart);
    kred<<<64, 128, 0, stream>>>(part, pospart, (float*)d_out);
}

// Round 23
// 65.592 us; speedup vs baseline: 1.0867x; 1.0867x over previous
//
#include <hip/hip_runtime.h>
#include <hip/hip_bf16.h>
#include <stdint.h>

#define NROWS 8192
#define DIM 512

typedef short bf16x8 __attribute__((ext_vector_type(8)));
typedef float f32x4 __attribute__((ext_vector_type(4)));

__device__ __forceinline__ unsigned short f2bf(float f) {
    union { float f; uint32_t u; } c; c.f = f;
    uint32_t u = c.u;
    return (unsigned short)((u + 0x7FFFu + ((u >> 16) & 1u)) >> 16);
}

__device__ __forceinline__ void gload16(const unsigned short* g, unsigned short* l) {
    __builtin_amdgcn_global_load_lds((const __attribute__((address_space(1))) void*)g,
                                     (__attribute__((address_space(3))) void*)l,
                                     16, 0, 0);
}

// ---------------- Kernel 1: L2-normalize rows -> bf16; zero out[0] + split-lin slots --
__global__ __launch_bounds__(256) void knorm(const float* __restrict__ in,
                                             unsigned short* __restrict__ out,
                                             float* __restrict__ part,
                                             float* __restrict__ loss_out) {
    if (blockIdx.x == 0 && threadIdx.x == 0) loss_out[0] = 0.0f;
    if (blockIdx.x < 16) {   // zero the 16 split-tile partial slots (quarters atomicAdd)
        part[((164 + blockIdx.x) << 9) + threadIdx.x] = 0.0f;
        part[((164 + blockIdx.x) << 9) + 256 + threadIdx.x] = 0.0f;
    }
    const int row  = (blockIdx.x << 2) + (threadIdx.x >> 6);
    const int lane = threadIdx.x & 63;
    const float4* src = (const float4*)(in + (size_t)row * DIM);
    float4 a = src[lane];
    float4 b = src[lane + 64];
    float ss = a.x*a.x + a.y*a.y + a.z*a.z + a.w*a.w
             + b.x*b.x + b.y*b.y + b.z*b.z + b.w*b.w;
    #pragma unroll
    for (int m = 1; m < 64; m <<= 1) ss += __shfl_xor(ss, m);
    const float inv = 1.0f / sqrtf(ss);
    ushort4* dst = (ushort4*)(out + (size_t)row * DIM);
    ushort4 o;
    o.x = f2bf(a.x*inv); o.y = f2bf(a.y*inv); o.z = f2bf(a.z*inv); o.w = f2bf(a.w*inv);
    dst[lane] = o;
    o.x = f2bf(b.x*inv); o.y = f2bf(b.y*inv); o.z = f2bf(b.z*inv); o.w = f2bf(b.w*inv);
    dst[lane + 64] = o;
}

// ---------------- Kernel 2 (R18 verbatim, session best: kgemm 47.2us / total 65.8us) --
// Tail-balanced grid: 512 full 256^2 tiles + 64 full-width quarter (128^2) tiles.
// Full path: BK=64, 8 convoys, counted vmcnt(4), proven 0-conflict swizzle,
// supertile XCD map, atomic-free streaming-store partial epilogue. Quarter
// path: all 16 waves (4x4 grid, 32x32/wave), vmcnt(2), atomicAdd into the 16
// pre-zeroed split slots. 512 heavy blocks = exactly 2 scheduling rounds; the
// 64 light blocks (~8.6us) fill the former third round.
__global__ __launch_bounds__(1024, 1) void kgemm(const unsigned short* __restrict__ E,
                                                 float* __restrict__ part,
                                                 float* __restrict__ pospart) {
    __shared__ unsigned short lds[2][2][256 * 64];   // full: 256 rows; quarter uses first 128

    const int tid = threadIdx.x;
    const int w = tid >> 6;          // 0..15
    const int l = tid & 63;
    const int xcd  = blockIdx.x & 7;
    const int slot = blockIdx.x >> 3;
    const int g_src = (l & 7) ^ (l >> 3);   // inverse-swizzled source 16B-group

    if (slot >= 64) {
        // ========== QUARTER: 128x128 pure-negative, ALL 16 waves (4x4 grid) ==========
        const int q  = (xcd << 3) + (slot - 64);     // 0..63
        const int p  = q >> 2;                       // parent 0..15
        const int lin = 164 + p;
        const int bi = p >> 3, bj = 24 + (p & 7);
        const int brow = (bi << 8) + (((q >> 1) & 1) << 7);
        const int bcol = (bj << 8) + ((q & 1) << 7);
        const int qroff = (((q >> 1) & 1) << 7);     // row offset within parent
        const int qcoff = ((q & 1) << 7);            // col offset within parent
        const int wr = (w >> 2) << 5;                // 0,32,64,96
        const int wc = (w & 3) << 5;                 // 0,32,64,96

        f32x4 acc[2][2];
        #pragma unroll
        for (int i = 0; i < 2; i++)
            #pragma unroll
            for (int j = 0; j < 2; j++) acc[i][j] = (f32x4)0.0f;

        auto STAGEQ = [&](int buf, int kt) {
            const size_t colb = (size_t)((kt << 6) + (g_src << 3));
            const int r = (w << 3) + (l >> 3);                   // 0..127
            gload16(E + (size_t)(brow + r) * DIM + colb, &lds[buf][0][w << 9]);
            gload16(E + (size_t)(bcol + r) * DIM + colb, &lds[buf][1][w << 9]);
        };
        auto COMPUTEQ = [&](int buf) {
            const unsigned short* sA = lds[buf][0];
            const unsigned short* sB = lds[buf][1];
            #pragma unroll
            for (int kk = 0; kk < 2; kk++) {
                bf16x8 aF[2], bF[2];
                const int gk  = (kk << 2) + (l >> 4);
                const int gsw = (gk ^ (l & 7)) << 3;
                #pragma unroll
                for (int mi = 0; mi < 2; mi++) {
                    const int rr = wr + (mi << 4) + (l & 15);
                    aF[mi] = *(const bf16x8*)&sA[(rr << 6) + gsw];
                }
                #pragma unroll
                for (int ni = 0; ni < 2; ni++) {
                    const int rr = wc + (ni << 4) + (l & 15);
                    bF[ni] = *(const bf16x8*)&sB[(rr << 6) + gsw];
                }
                #pragma unroll
                for (int mi = 0; mi < 2; mi++)
                    #pragma unroll
                    for (int ni = 0; ni < 2; ni++)
                        acc[mi][ni] = __builtin_amdgcn_mfma_f32_16x16x32_bf16(
                            aF[mi], bF[ni], acc[mi][ni], 0, 0, 0);
            }
        };

        STAGEQ(0, 0);
        #pragma unroll
        for (int kt = 0; kt < 8; kt++) {
            if (kt > 0) __builtin_amdgcn_s_barrier();
            if (kt < 7) {
                STAGEQ((kt + 1) & 1, kt + 1);
                asm volatile("s_waitcnt vmcnt(2)" ::: "memory");
            } else {
                asm volatile("s_waitcnt vmcnt(0)" ::: "memory");
            }
            __builtin_amdgcn_sched_barrier(0);
            __builtin_amdgcn_s_barrier();
            COMPUTEQ(kt & 1);
        }

        float c[2] = {0.0f, 0.0f};
        #pragma unroll
        for (int mi = 0; mi < 2; mi++) {
            #pragma unroll
            for (int r = 0; r < 4; r++) {
                const int lrow = wr + (mi << 4) + ((l >> 4) << 2) + r;  // 0..127
                float n = 0.0f;
                #pragma unroll
                for (int ni = 0; ni < 2; ni++) {
                    const float e = __expf(fmaf(acc[mi][ni][r], 10.0f, -10.0f));
                    n += e;
                    c[ni] += e;
                }
                #pragma unroll
                for (int m = 1; m < 16; m <<= 1) n += __shfl_xor(n, m);
                if ((l & 15) == 0)
                    atomicAdd(&part[((size_t)lin << 9) + qroff + lrow], n);
            }
        }
        #pragma unroll
        for (int ni = 0; ni < 2; ni++) {
            c[ni] += __shfl_xor(c[ni], 16);
            c[ni] += __shfl_xor(c[ni], 32);
            if ((l >> 4) == 0)
                atomicAdd(&part[((size_t)lin << 9) + 256 + qcoff + wc + (ni << 4) + l],
                          c[ni]);
        }
        return;
    }

    // ================= FULL: 256x256 tile =============================
    const int f   = (xcd << 6) + slot;               // 0..511
    const int lin = f + (f >= 164 ? 16 : 0);         // skip split set 164..179
    int rem = lin;
    int SI = -1, SJ = -1;
    #pragma unroll
    for (int s = 0; s < 10; s++) {
        constexpr int si_t[10] = {0,0,0,0,1,1,1,2,2,3};
        constexpr int sj_t[10] = {0,1,2,3,1,2,3,2,3,3};
        const int sz = (si_t[s] == sj_t[s]) ? 36 : 64;
        if (SI < 0) {
            if (rem < sz) { SI = si_t[s]; SJ = sj_t[s]; }
            else rem -= sz;
        }
    }
    int bi, bj;
    if (SI == SJ) {
        int x = 0;
        while (rem >= 8 - x) { rem -= 8 - x; x++; }
        bi = (SI << 3) + x; bj = (SI << 3) + x + rem;
    } else {
        bi = (SI << 3) + (rem >> 3);
        bj = (SJ << 3) + (rem & 7);
    }

    const int brow = bi << 8;
    const int bcol = bj << 8;
    const int wr = (w >> 2) << 6;
    const int wc = (w & 3) << 6;

    f32x4 acc[4][4];
    #pragma unroll
    for (int i = 0; i < 4; i++)
        #pragma unroll
        for (int j = 0; j < 4; j++) acc[i][j] = (f32x4)0.0f;

    auto STAGE = [&](int buf, int kt) {
        const size_t colb = (size_t)((kt << 6) + (g_src << 3));
        #pragma unroll
        for (int s = 0; s < 2; s++) {
            const int rb = (w << 4) + (s << 3);
            const int r  = rb + (l >> 3);
            gload16(E + (size_t)(brow + r) * DIM + colb, &lds[buf][0][rb << 6]);
            gload16(E + (size_t)(bcol + r) * DIM + colb, &lds[buf][1][rb << 6]);
        }
    };

    auto COMPUTE = [&](int buf) {
        const unsigned short* sA = lds[buf][0];
        const unsigned short* sB = lds[buf][1];
        #pragma unroll
        for (int kk = 0; kk < 2; kk++) {
            bf16x8 aF[4], bF[4];
            const int gk  = (kk << 2) + (l >> 4);
            const int gsw = (gk ^ (l & 7)) << 3;
            #pragma unroll
            for (int mi = 0; mi < 4; mi++) {
                const int rr = wr + (mi << 4) + (l & 15);
                aF[mi] = *(const bf16x8*)&sA[(rr << 6) + gsw];
            }
            #pragma unroll
            for (int ni = 0; ni < 4; ni++) {
                const int rr = wc + (ni << 4) + (l & 15);
                bF[ni] = *(const bf16x8*)&sB[(rr << 6) + gsw];
            }
            #pragma unroll
            for (int mi = 0; mi < 4; mi++)
                #pragma unroll
                for (int ni = 0; ni < 4; ni++)
                    acc[mi][ni] = __builtin_amdgcn_mfma_f32_16x16x32_bf16(
                        aF[mi], bF[ni], acc[mi][ni], 0, 0, 0);
        }
    };

    STAGE(0, 0);
    #pragma unroll
    for (int kt = 0; kt < 8; kt++) {
        if (kt > 0) __builtin_amdgcn_s_barrier();
        if (kt < 7) {
            STAGE((kt + 1) & 1, kt + 1);
            asm volatile("s_waitcnt vmcnt(4)" ::: "memory");
        } else {
            asm volatile("s_waitcnt vmcnt(0)" ::: "memory");
        }
        __builtin_amdgcn_sched_barrier(0);
        __builtin_amdgcn_s_barrier();
        COMPUTE(kt & 1);
    }

    float* lds_row = (float*)&lds[0][0][0];       // [4][256]
    float* lds_col = lds_row + 1024;              // [4][256]
    float* lds_pos = lds_row + 2048;              // [4][256]

    __syncthreads();

    if (bi == bj) {
        #pragma unroll
        for (int mi = 0; mi < 4; mi++) {
            #pragma unroll
            for (int r = 0; r < 4; r++) {
                const int lrow = wr + (mi << 4) + ((l >> 4) << 2) + r;
                const int gi = brow + lrow;
                float p = 0.0f, n = 0.0f;
                #pragma unroll
                for (int ni = 0; ni < 4; ni++) {
                    const int gj = bcol + wc + (ni << 4) + (l & 15);
                    const float e = __expf(fmaf(acc[mi][ni][r], 10.0f, -10.0f));
                    if (gi == gj) {
                    } else if ((gi >> 2) == (gj >> 2)) {
                        p += e;
                    } else {
                        n += e;
                    }
                }
                #pragma unroll
                for (int m = 1; m < 16; m <<= 1) {
                    n += __shfl_xor(n, m);
                    p += __shfl_xor(p, m);
                }
                if ((l & 15) == 0) {
                    lds_row[((w & 3) << 8) + lrow] = n;
                    lds_pos[((w & 3) << 8) + lrow] = p;
                }
            }
        }
    } else {
        float c[4] = {0.0f, 0.0f, 0.0f, 0.0f};
        #pragma unroll
        for (int mi = 0; mi < 4; mi++) {
            #pragma unroll
            for (int r = 0; r < 4; r++) {
                const int lrow = wr + (mi << 4) + ((l >> 4) << 2) + r;
                float n = 0.0f;
                #pragma unroll
                for (int ni = 0; ni < 4; ni++) {
                    const float e = __expf(fmaf(acc[mi][ni][r], 10.0f, -10.0f));
                    n += e;
                    c[ni] += e;
                }
                #pragma unroll
                for (int m = 1; m < 16; m <<= 1) n += __shfl_xor(n, m);
                if ((l & 15) == 0) lds_row[((w & 3) << 8) + lrow] = n;
            }
        }
        #pragma unroll
        for (int ni = 0; ni < 4; ni++) {
            c[ni] += __shfl_xor(c[ni], 16);
            c[ni] += __shfl_xor(c[ni], 32);
            if ((l >> 4) == 0)
                lds_col[((w >> 2) << 8) + wc + (ni << 4) + l] = c[ni];
        }
    }
    __syncthreads();

    if (tid < 256) {
        const float s = lds_row[tid] + lds_row[256 + tid]
                      + lds_row[512 + tid] + lds_row[768 + tid];
        part[((size_t)lin << 9) + tid] = s;
    } else if (tid < 512) {
        if (bi != bj) {
            const int cc = tid - 256;
            const float s = lds_col[cc] + lds_col[256 + cc]
                          + lds_col[512 + cc] + lds_col[768 + cc];
            part[((size_t)lin << 9) + 256 + cc] = s;
        }
    } else if (tid < 768) {
        if (bi == bj) {
            const int rr = tid - 512;
            const float s = lds_pos[rr] + lds_pos[256 + rr]
                          + lds_pos[512 + rr] + lds_pos[768 + rr];
            pospart[(bi << 8) + rr] = s;
        }
    }
}

// ---------------- Kernel 3: gather partials, compute loss, reduce ----------------
__global__ __launch_bounds__(128) void kred(const float* __restrict__ part,
                                            const float* __restrict__ pospart,
                                            float* __restrict__ out) {
    const int T = blockIdx.x >> 1;
    const int r = ((blockIdx.x & 1) << 7) + threadIdx.x;   // 0..255 within T's group

    auto linof = [](int a, int b) {   // a <= b, 0..31
        constexpr int base[4][4] = {{0, 36, 100, 164},
                                    {0, 228, 264, 328},
                                    {0, 0, 392, 428},
                                    {0, 0, 0, 492}};
        const int SI = a >> 3, SJ = b >> 3, x = a & 7, y = b & 7;
        int inner;
        if (SI == SJ) inner = (x << 3) - ((x * (x - 1)) >> 1) + (y - x);
        else          inner = (x << 3) + y;
        return base[SI][SJ] + inner;
    };

    float n = 0.0f;
    for (int bj = T; bj < 32; bj++)
        n += part[((size_t)linof(T, bj) << 9) + r];
    for (int bi = 0; bi < T; bi++)
        n += part[((size_t)linof(bi, T) << 9) + 256 + r];
    const float p = pospart[(T << 8) + r];

    float s = __logf(p + n + 1e-8f) - __logf(p);
    #pragma unroll
    for (int m = 1; m < 64; m <<= 1) s += __shfl_xor(s, m);
    __shared__ float red[2];
    if ((threadIdx.x & 63) == 0) red[threadIdx.x >> 6] = s;
    __syncthreads();
    if (threadIdx.x == 0)
        atomicAdd(out, (red[0] + red[1]) * (1.0f / (float)NROWS));
}

extern "C" void kernel_launch(void* const* d_in, const int* in_sizes, int n_in,
                              void* d_out, int out_size, void* d_ws, size_t ws_size,
                              hipStream_t stream) {
    (void)in_sizes; (void)n_in; (void)out_size; (void)ws_size;
    const float* emb = (const float*)d_in[0];
    unsigned short* En = (unsigned short*)d_ws;                          // 8 MB bf16
    float* pospart = (float*)((char*)d_ws + (size_t)NROWS * DIM * 2);    // 32 KB
    float* part    = pospart + 32 * 256;                                 // 1.05 MB

    knorm<<<NROWS / 4, 256, 0, stream>>>(emb, En, part, (float*)d_out);
    kgemm<<<576, 1024, 0, stream>>>(En, part, pospart);
    kred<<<64, 128, 0, stream>>>(part, pospart, (float*)d_out);
}